// Round 6
// baseline (214.303 us; speedup 1.0000x reference)
//
#include <hip/hip_runtime.h>

// Weighted BCE over (N=4, C=3, 128^3) fp32.
// Identity (t in {0,1} exactly): t*log(p)+(1-t)*log(1-p) = log(t ? p : 1-p);
// count(t!=0) = sum(t) (float-exact below 2^24).
//
// R5 post-mortem: plateau at ~73 us (2.75 TB/s delivered) with ALL pipes idle
// (VALU 16%, HBM 17%) and VGPR_Count=32 -> the scheduler sinks loads to uses
// (~2 KB/wave in flight) and queue-inflated latency caps BW (Little's law).
// R6: depth-4 ROTATING pipeline (each slot consumed one round after its
// prefetch -> live ranges force 8 loads in flight) + __launch_bounds__(256,2)
// so the allocator is permitted the ~60-90 VGPRs this needs.

#define THREADS 256
#define BLOCKS_PER_SLAB 128
#define NSLABS 12            // N*C = 4*3
#define NCHAN 3
#define ENTRIES_PER_CHAN (4 * BLOCKS_PER_SLAB)   // 4 slabs per channel -> 512
// per-thread float4 pairs: 524288 / (128*256) = 16 -> 4 rounds of 4, depth-4 pipe

__device__ __forceinline__ void acc4(float4 p, float4 t, float& lsum, float& lcnt)
{
    float pp[4] = {p.x, p.y, p.z, p.w};
    float tt[4] = {t.x, t.y, t.z, t.w};
#pragma unroll
    for (int k = 0; k < 4; ++k) {
        bool  pos = (tt[k] != 0.0f);
        float x   = pos ? pp[k] : (1.0f - pp[k]);   // cmp + sub + cndmask
        lsum += fmaxf(__logf(x), -100.0f);          // one v_log_f32
        lcnt += tt[k];                               // exact count
    }
}

__global__ __launch_bounds__(THREADS, 2) void bce_partial(
    const float* __restrict__ input,
    const float* __restrict__ target,
    float* __restrict__ psum,    // [3*512]
    float* __restrict__ pcnt,    // [3*512]
    int S4)                       // float4 per slab (524288)
{
    const int slab = blockIdx.x / BLOCKS_PER_SLAB;
    const int blk  = blockIdx.x % BLOCKS_PER_SLAB;
    const int c    = slab % NCHAN;              // block-uniform

    const float4* __restrict__ in4 = (const float4*)input  + (size_t)slab * S4;
    const float4* __restrict__ tg4 = (const float4*)target + (size_t)slab * S4;

    const int stride = BLOCKS_PER_SLAB * THREADS;   // 32768 float4
    const int i = blk * THREADS + (int)threadIdx.x;

    // ---- depth-4 rotating software pipeline: 8 loads always in flight ----
    float4 P0 = in4[i];              float4 T0 = tg4[i];
    float4 P1 = in4[i +     stride]; float4 T1 = tg4[i +     stride];
    float4 P2 = in4[i + 2 * stride]; float4 T2 = tg4[i + 2 * stride];
    float4 P3 = in4[i + 3 * stride]; float4 T3 = tg4[i + 3 * stride];

    float lsum = 0.0f, lcnt = 0.0f;

#pragma unroll
    for (int r = 0; r < 3; ++r) {
        const int b = i + (r + 1) * 4 * stride;
        acc4(P0, T0, lsum, lcnt); P0 = in4[b];              T0 = tg4[b];
        acc4(P1, T1, lsum, lcnt); P1 = in4[b +     stride]; T1 = tg4[b +     stride];
        acc4(P2, T2, lsum, lcnt); P2 = in4[b + 2 * stride]; T2 = tg4[b + 2 * stride];
        acc4(P3, T3, lsum, lcnt); P3 = in4[b + 3 * stride]; T3 = tg4[b + 3 * stride];
    }
    // epilogue: drain the pipeline (pairs 12..15)
    acc4(P0, T0, lsum, lcnt);
    acc4(P1, T1, lsum, lcnt);
    acc4(P2, T2, lsum, lcnt);
    acc4(P3, T3, lsum, lcnt);

    // wave (64-lane) reduction
#pragma unroll
    for (int off = 32; off > 0; off >>= 1) {
        lsum += __shfl_down(lsum, off, 64);
        lcnt += __shfl_down(lcnt, off, 64);
    }

    __shared__ float wsum[THREADS / 64];
    __shared__ float wcnt[THREADS / 64];
    const int lane = threadIdx.x & 63;
    const int wave = threadIdx.x >> 6;
    if (lane == 0) { wsum[wave] = lsum; wcnt[wave] = lcnt; }
    __syncthreads();
    if (threadIdx.x == 0) {
        float s = 0.0f, n = 0.0f;
#pragma unroll
        for (int w = 0; w < THREADS / 64; ++w) { s += wsum[w]; n += wcnt[w]; }
        const int e = c * ENTRIES_PER_CHAN + (slab / NCHAN) * BLOCKS_PER_SLAB + blk;
        psum[e] = s;          // plain stores, distinct addresses: NO atomics
        pcnt[e] = n;
    }
}

__global__ __launch_bounds__(THREADS) void bce_final(
    const float* __restrict__ psum,
    const float* __restrict__ pcnt,
    float* __restrict__ out,
    float per_chan_total)
{
    const int tid = (int)threadIdx.x;
    float s[NCHAN], n[NCHAN];
#pragma unroll
    for (int c = 0; c < NCHAN; ++c) {
        const int b = c * ENTRIES_PER_CHAN + tid;
        s[c] = psum[b] + psum[b + THREADS];
        n[c] = pcnt[b] + pcnt[b + THREADS];
    }
#pragma unroll
    for (int off = 32; off > 0; off >>= 1) {
#pragma unroll
        for (int c = 0; c < NCHAN; ++c) {
            s[c] += __shfl_down(s[c], off, 64);
            n[c] += __shfl_down(n[c], off, 64);
        }
    }
    __shared__ float ws[THREADS / 64][NCHAN], wn[THREADS / 64][NCHAN];
    const int lane = tid & 63, wave = tid >> 6;
    if (lane == 0) {
#pragma unroll
        for (int c = 0; c < NCHAN; ++c) { ws[wave][c] = s[c]; wn[wave][c] = n[c]; }
    }
    __syncthreads();
    if (tid == 0) {
        float acc = 0.0f;
#pragma unroll
        for (int c = 0; c < NCHAN; ++c) {
            float ssum = 0.0f, ncnt = 0.0f;
#pragma unroll
            for (int w = 0; w < THREADS / 64; ++w) { ssum += ws[w][c]; ncnt += wn[w][c]; }
            float w8  = (ncnt > 0.0f) ? (per_chan_total / fmaxf(ncnt, 1.0f)) : 1000.0f;
            float bce = -(ssum / per_chan_total);
            acc += w8 * bce;
        }
        out[0] = acc / (float)NCHAN;
    }
}

extern "C" void kernel_launch(void* const* d_in, const int* in_sizes, int n_in,
                              void* d_out, int out_size, void* d_ws, size_t ws_size,
                              hipStream_t stream)
{
    const float* input  = (const float*)d_in[0];
    const float* target = (const float*)d_in[1];
    float*       out    = (float*)d_out;

    const int nentry = NCHAN * ENTRIES_PER_CHAN;          // 1536
    float* psum = (float*)d_ws;
    float* pcnt = (float*)d_ws + nentry;

    const long long total = (long long)in_sizes[0];        // 25,165,824
    const int       S4    = (int)(total / (NSLABS * 4));    // 524,288
    const float     M     = (float)(total / NCHAN);         // 8,388,608

    bce_partial<<<NSLABS * BLOCKS_PER_SLAB, THREADS, 0, stream>>>(
        input, target, psum, pcnt, S4);
    bce_final<<<1, THREADS, 0, stream>>>(psum, pcnt, out, M);
}

// Round 7
// 212.945 us; speedup vs baseline: 1.0064x; 1.0064x over previous
//
#include <hip/hip_runtime.h>

// Weighted BCE over (N=4, C=3, 128^3) fp32.
// Identity (t in {0,1} exactly): t*log(p)+(1-t)*log(1-p) = log(t ? p : 1-p);
// count(t!=0) = sum(t) (float-exact below 2^24).
//
// R6 post-mortem: 3rd failed attempt to force load-ILP through VGPRs
// (VGPR_Count=36 proves the compiler re-sank the rotating pipeline).
// R7: bypass the register allocator entirely -- global_load_lds DMA into
// WAVE-PRIVATE triple-buffered LDS. No __syncthreads in the stream loop
// (each wave reads only its own staging region), completion via explicit
// s_waitcnt vmcnt(4) -- always one full stage (4 KB/wave) in flight.

#define THREADS 256
#define WAVES (THREADS / 64)
#define BLOCKS_PER_SLAB 128
#define NSLABS 12            // N*C
#define NCHAN 3
#define ENTRIES_PER_CHAN (4 * BLOCKS_PER_SLAB)   // 512

// staging geometry (per wave): stage = 2 KB input + 2 KB target = 4 instrs
#define STAGE_F4 128                   // float4 per array per stage (2 KB)
#define INSTR_PER_ARRAY 2              // 2 x (16 B x 64 lanes)
#define NSTAGE 8                       // per-wave chunk = 1024 float4 per array
#define NBUF 3                         // triple buffer: read / in-flight / issue
#define BUF_BYTES 4096                 // 2 KB in + 2 KB tg
#define WAVE_LDS (NBUF * BUF_BYTES)    // 12 KB
#define BLOCK_LDS (WAVES * WAVE_LDS)   // 48 KB -> 3 blocks/CU

// s_waitcnt imm (gfx9 encoding): vmcnt[3:0], expcnt=7 [6:4], lgkmcnt=15 [11:8]
#define WAITVM(N) __builtin_amdgcn_s_waitcnt(0x0F70 | (N))

typedef __attribute__((address_space(1))) const void gvoid_t;
typedef __attribute__((address_space(3))) void lvoid_t;

__device__ __forceinline__ void stage_issue(
    const float4* __restrict__ gin, const float4* __restrict__ gtg,
    int f4idx, char* lbuf /*wave-uniform*/, int lane)
{
    // LDS dest is wave-uniform base; HW scatters lane i at +i*16.
#pragma unroll
    for (int q = 0; q < INSTR_PER_ARRAY; ++q)
        __builtin_amdgcn_global_load_lds(
            (gvoid_t*)(gin + f4idx + q * 64 + lane),
            (lvoid_t*)(lbuf + q * 1024), 16, 0, 0);
#pragma unroll
    for (int q = 0; q < INSTR_PER_ARRAY; ++q)
        __builtin_amdgcn_global_load_lds(
            (gvoid_t*)(gtg + f4idx + q * 64 + lane),
            (lvoid_t*)(lbuf + 2048 + q * 1024), 16, 0, 0);
}

__device__ __forceinline__ void acc4(float4 p, float4 t, float& lsum, float& lcnt)
{
    float pp[4] = {p.x, p.y, p.z, p.w};
    float tt[4] = {t.x, t.y, t.z, t.w};
#pragma unroll
    for (int k = 0; k < 4; ++k) {
        bool  pos = (tt[k] != 0.0f);
        float x   = pos ? pp[k] : (1.0f - pp[k]);
        lsum += fmaxf(__logf(x), -100.0f);          // one v_log_f32
        lcnt += tt[k];
    }
}

__global__ __launch_bounds__(THREADS) void bce_partial(
    const float* __restrict__ input,
    const float* __restrict__ target,
    float* __restrict__ psum,    // [3*512]
    float* __restrict__ pcnt,    // [3*512]
    int S4)                       // float4 per slab (524288)
{
    __shared__ __align__(16) char smem[BLOCK_LDS];

    const int slab = blockIdx.x / BLOCKS_PER_SLAB;
    const int blk  = blockIdx.x % BLOCKS_PER_SLAB;
    const int c    = slab % NCHAN;              // block-uniform

    const int lane = threadIdx.x & 63;
    const int wv   = threadIdx.x >> 6;

    const float4* __restrict__ in4 = (const float4*)input  + (size_t)slab * S4;
    const float4* __restrict__ tg4 = (const float4*)target + (size_t)slab * S4;

    // per-wave contiguous chunk of 1024 float4 per array
    const int chunk = (blk * WAVES + wv) * (NSTAGE * STAGE_F4);
    char* wlds = smem + wv * WAVE_LDS;          // wave-private region

    // prologue: 2 stages in flight (8 vmem instrs, 8 KB)
    stage_issue(in4, tg4, chunk + 0 * STAGE_F4, wlds + 0 * BUF_BYTES, lane);
    stage_issue(in4, tg4, chunk + 1 * STAGE_F4, wlds + 1 * BUF_BYTES, lane);

    float lsum = 0.0f, lcnt = 0.0f;

#pragma unroll
    for (int j = 0; j < NSTAGE; ++j) {
        // stage j complete when <= 4 vmem ops outstanding (stage j+1's)
        if (j < NSTAGE - 1) WAITVM(4); else WAITVM(0);
        __builtin_amdgcn_sched_barrier(0);      // no ds_read hoisted above wait

        const float4* buf = (const float4*)(wlds + (j % NBUF) * BUF_BYTES);
#pragma unroll
        for (int q = 0; q < INSTR_PER_ARRAY; ++q) {
            float4 p = buf[q * 64 + lane];          // own staged data
            float4 t = buf[128 + q * 64 + lane];
            acc4(p, t, lsum, lcnt);
        }
        __builtin_amdgcn_sched_barrier(0);      // issue stays after reads

        if (j + 2 < NSTAGE)                      // buffer (j+2)%3 is idle
            stage_issue(in4, tg4, chunk + (j + 2) * STAGE_F4,
                        wlds + ((j + 2) % NBUF) * BUF_BYTES, lane);
    }

    // ---- block reduction (no atomics; plain stores to distinct addrs) ----
#pragma unroll
    for (int off = 32; off > 0; off >>= 1) {
        lsum += __shfl_down(lsum, off, 64);
        lcnt += __shfl_down(lcnt, off, 64);
    }

    __shared__ float wsum[WAVES];
    __shared__ float wcnt[WAVES];
    if (lane == 0) { wsum[wv] = lsum; wcnt[wv] = lcnt; }
    __syncthreads();
    if (threadIdx.x == 0) {
        float s = 0.0f, n = 0.0f;
#pragma unroll
        for (int w = 0; w < WAVES; ++w) { s += wsum[w]; n += wcnt[w]; }
        const int e = c * ENTRIES_PER_CHAN + (slab / NCHAN) * BLOCKS_PER_SLAB + blk;
        psum[e] = s;
        pcnt[e] = n;
    }
}

__global__ __launch_bounds__(THREADS) void bce_final(
    const float* __restrict__ psum,
    const float* __restrict__ pcnt,
    float* __restrict__ out,
    float per_chan_total)
{
    const int tid = (int)threadIdx.x;
    float s[NCHAN], n[NCHAN];
#pragma unroll
    for (int c = 0; c < NCHAN; ++c) {
        const int b = c * ENTRIES_PER_CHAN + tid;
        s[c] = psum[b] + psum[b + THREADS];
        n[c] = pcnt[b] + pcnt[b + THREADS];
    }
#pragma unroll
    for (int off = 32; off > 0; off >>= 1) {
#pragma unroll
        for (int c = 0; c < NCHAN; ++c) {
            s[c] += __shfl_down(s[c], off, 64);
            n[c] += __shfl_down(n[c], off, 64);
        }
    }
    __shared__ float ws[THREADS / 64][NCHAN], wn[THREADS / 64][NCHAN];
    const int lane = tid & 63, wave = tid >> 6;
    if (lane == 0) {
#pragma unroll
        for (int c = 0; c < NCHAN; ++c) { ws[wave][c] = s[c]; wn[wave][c] = n[c]; }
    }
    __syncthreads();
    if (tid == 0) {
        float acc = 0.0f;
#pragma unroll
        for (int c = 0; c < NCHAN; ++c) {
            float ssum = 0.0f, ncnt = 0.0f;
#pragma unroll
            for (int w = 0; w < THREADS / 64; ++w) { ssum += ws[w][c]; ncnt += wn[w][c]; }
            float w8  = (ncnt > 0.0f) ? (per_chan_total / fmaxf(ncnt, 1.0f)) : 1000.0f;
            float bce = -(ssum / per_chan_total);
            acc += w8 * bce;
        }
        out[0] = acc / (float)NCHAN;
    }
}

extern "C" void kernel_launch(void* const* d_in, const int* in_sizes, int n_in,
                              void* d_out, int out_size, void* d_ws, size_t ws_size,
                              hipStream_t stream)
{
    const float* input  = (const float*)d_in[0];
    const float* target = (const float*)d_in[1];
    float*       out    = (float*)d_out;

    const int nentry = NCHAN * ENTRIES_PER_CHAN;          // 1536
    float* psum = (float*)d_ws;
    float* pcnt = (float*)d_ws + nentry;

    const long long total = (long long)in_sizes[0];        // 25,165,824
    const int       S4    = (int)(total / (NSLABS * 4));    // 524,288
    const float     M     = (float)(total / NCHAN);         // 8,388,608

    bce_partial<<<NSLABS * BLOCKS_PER_SLAB, THREADS, 0, stream>>>(
        input, target, psum, pcnt, S4);
    bce_final<<<1, THREADS, 0, stream>>>(psum, pcnt, out, M);
}

// Round 8
// 197.492 us; speedup vs baseline: 1.0851x; 1.0782x over previous
//
#include <hip/hip_runtime.h>

// Weighted BCE over (N=4, C=3, 128^3) fp32.
// Identity (t in {0,1} exactly): t*log(p)+(1-t)*log(1-p) = log(t ? p : 1-p);
// count(t!=0) = sum(t) (float-exact below 2^24).
//
// R7 post-mortem: guaranteed 8 KB/wave in flight (LDS-DMA + vmcnt pipeline)
// did NOT move BW -> not an MLP problem. All variants saturate ~2.7 TB/s
// read; FETCH_SIZE 98 MB is the gfx94x formula undercounting 2x (=> full
// 201 MB misses to fabric). Copy read-side = 3.15 TB/s, RMSNorm read = 2.45:
// the cold-read path lives near ~3 TB/s.
// R8: last qualitative lever -- nontemporal (no-allocate) loads to remove
// L2 line-install/evict churn for this zero-reuse stream.

#define THREADS 256
#define BLOCKS_PER_SLAB 128
#define NSLABS 12            // N*C = 4*3
#define NCHAN 3
#define ENTRIES_PER_CHAN (4 * BLOCKS_PER_SLAB)   // 512

typedef float v4f __attribute__((ext_vector_type(4)));

__device__ __forceinline__ v4f ntload(const v4f* __restrict__ p)
{
    return __builtin_nontemporal_load(p);
}

__device__ __forceinline__ void acc4(v4f p, v4f t, float& lsum, float& lcnt)
{
#pragma unroll
    for (int k = 0; k < 4; ++k) {
        bool  pos = (t[k] != 0.0f);
        float x   = pos ? p[k] : (1.0f - p[k]);   // cmp + sub + cndmask
        lsum += fmaxf(__logf(x), -100.0f);        // one v_log_f32
        lcnt += t[k];                              // exact count
    }
}

__global__ __launch_bounds__(THREADS) void bce_partial(
    const float* __restrict__ input,
    const float* __restrict__ target,
    float* __restrict__ psum,    // [3*512]
    float* __restrict__ pcnt,    // [3*512]
    int S4)                       // float4 per slab (524288)
{
    const int slab = blockIdx.x / BLOCKS_PER_SLAB;
    const int blk  = blockIdx.x % BLOCKS_PER_SLAB;
    const int c    = slab % NCHAN;              // block-uniform

    const v4f* __restrict__ in4 = (const v4f*)input  + (size_t)slab * S4;
    const v4f* __restrict__ tg4 = (const v4f*)target + (size_t)slab * S4;

    float lsum = 0.0f, lcnt = 0.0f;

    const int stride = BLOCKS_PER_SLAB * THREADS;   // 32768 float4
    int i = blk * THREADS + (int)threadIdx.x;

    for (; i + 3 * stride < S4; i += 4 * stride) {
        v4f p0 = ntload(in4 + i);
        v4f p1 = ntload(in4 + i +     stride);
        v4f p2 = ntload(in4 + i + 2 * stride);
        v4f p3 = ntload(in4 + i + 3 * stride);
        v4f t0 = ntload(tg4 + i);
        v4f t1 = ntload(tg4 + i +     stride);
        v4f t2 = ntload(tg4 + i + 2 * stride);
        v4f t3 = ntload(tg4 + i + 3 * stride);
        acc4(p0, t0, lsum, lcnt);
        acc4(p1, t1, lsum, lcnt);
        acc4(p2, t2, lsum, lcnt);
        acc4(p3, t3, lsum, lcnt);
    }
    for (; i < S4; i += stride)   // remainder (none for 524288)
        acc4(ntload(in4 + i), ntload(tg4 + i), lsum, lcnt);

    // wave (64-lane) reduction
#pragma unroll
    for (int off = 32; off > 0; off >>= 1) {
        lsum += __shfl_down(lsum, off, 64);
        lcnt += __shfl_down(lcnt, off, 64);
    }

    __shared__ float wsum[THREADS / 64];
    __shared__ float wcnt[THREADS / 64];
    const int lane = threadIdx.x & 63;
    const int wave = threadIdx.x >> 6;
    if (lane == 0) { wsum[wave] = lsum; wcnt[wave] = lcnt; }
    __syncthreads();
    if (threadIdx.x == 0) {
        float s = 0.0f, n = 0.0f;
#pragma unroll
        for (int w = 0; w < THREADS / 64; ++w) { s += wsum[w]; n += wcnt[w]; }
        const int e = c * ENTRIES_PER_CHAN + (slab / NCHAN) * BLOCKS_PER_SLAB + blk;
        psum[e] = s;          // plain stores, distinct addresses: NO atomics
        pcnt[e] = n;
    }
}

__global__ __launch_bounds__(THREADS) void bce_final(
    const float* __restrict__ psum,
    const float* __restrict__ pcnt,
    float* __restrict__ out,
    float per_chan_total)
{
    const int tid = (int)threadIdx.x;
    float s[NCHAN], n[NCHAN];
#pragma unroll
    for (int c = 0; c < NCHAN; ++c) {
        const int b = c * ENTRIES_PER_CHAN + tid;
        s[c] = psum[b] + psum[b + THREADS];
        n[c] = pcnt[b] + pcnt[b + THREADS];
    }
#pragma unroll
    for (int off = 32; off > 0; off >>= 1) {
#pragma unroll
        for (int c = 0; c < NCHAN; ++c) {
            s[c] += __shfl_down(s[c], off, 64);
            n[c] += __shfl_down(n[c], off, 64);
        }
    }
    __shared__ float ws[THREADS / 64][NCHAN], wn[THREADS / 64][NCHAN];
    const int lane = tid & 63, wave = tid >> 6;
    if (lane == 0) {
#pragma unroll
        for (int c = 0; c < NCHAN; ++c) { ws[wave][c] = s[c]; wn[wave][c] = n[c]; }
    }
    __syncthreads();
    if (tid == 0) {
        float acc = 0.0f;
#pragma unroll
        for (int c = 0; c < NCHAN; ++c) {
            float ssum = 0.0f, ncnt = 0.0f;
#pragma unroll
            for (int w = 0; w < THREADS / 64; ++w) { ssum += ws[w][c]; ncnt += wn[w][c]; }
            float w8  = (ncnt > 0.0f) ? (per_chan_total / fmaxf(ncnt, 1.0f)) : 1000.0f;
            float bce = -(ssum / per_chan_total);
            acc += w8 * bce;
        }
        out[0] = acc / (float)NCHAN;
    }
}

extern "C" void kernel_launch(void* const* d_in, const int* in_sizes, int n_in,
                              void* d_out, int out_size, void* d_ws, size_t ws_size,
                              hipStream_t stream)
{
    const float* input  = (const float*)d_in[0];
    const float* target = (const float*)d_in[1];
    float*       out    = (float*)d_out;

    const int nentry = NCHAN * ENTRIES_PER_CHAN;          // 1536
    float* psum = (float*)d_ws;
    float* pcnt = (float*)d_ws + nentry;

    const long long total = (long long)in_sizes[0];        // 25,165,824
    const int       S4    = (int)(total / (NSLABS * 4));    // 524,288
    const float     M     = (float)(total / NCHAN);         // 8,388,608

    bce_partial<<<NSLABS * BLOCKS_PER_SLAB, THREADS, 0, stream>>>(
        input, target, psum, pcnt, S4);
    bce_final<<<1, THREADS, 0, stream>>>(psum, pcnt, out, M);
}

// Round 9
// 194.024 us; speedup vs baseline: 1.1045x; 1.0179x over previous
//
#include <hip/hip_runtime.h>

// Weighted BCE over (N=4, C=3, 128^3) fp32.
// Identity (t in {0,1} exactly): t*log(p)+(1-t)*log(1-p) = log(t ? p : 1-p);
// count(t!=0) = sum(t) (float-exact below 2^24).
//
// R8 post-mortem: WIN -- nontemporal loads removed L2 line-install churn,
// partial 74.8 -> ~59 us (3.4 TB/s read). fillBuffer shows 6.8 TB/s
// write-only, so fabric has headroom; reads need outstanding-request slots.
// R9: raise TLP -- 256 blocks/slab (3072 blocks = 12/CU queued, 32 waves/CU
// resident + backfill). Atomics long gone, so no convoy risk.

#define THREADS 256
#define BLOCKS_PER_SLAB 256
#define NSLABS 12            // N*C = 4*3
#define NCHAN 3
#define ENTRIES_PER_CHAN (4 * BLOCKS_PER_SLAB)   // 1024
#define EPT (ENTRIES_PER_CHAN / THREADS)         // stage-2 entries/thread = 4

typedef float v4f __attribute__((ext_vector_type(4)));

__device__ __forceinline__ v4f ntload(const v4f* __restrict__ p)
{
    return __builtin_nontemporal_load(p);
}

__device__ __forceinline__ void acc4(v4f p, v4f t, float& lsum, float& lcnt)
{
#pragma unroll
    for (int k = 0; k < 4; ++k) {
        bool  pos = (t[k] != 0.0f);
        float x   = pos ? p[k] : (1.0f - p[k]);   // cmp + sub + cndmask
        lsum += fmaxf(__logf(x), -100.0f);        // one v_log_f32
        lcnt += t[k];                              // exact count
    }
}

__global__ __launch_bounds__(THREADS) void bce_partial(
    const float* __restrict__ input,
    const float* __restrict__ target,
    float* __restrict__ psum,    // [3*1024]
    float* __restrict__ pcnt,    // [3*1024]
    int S4)                       // float4 per slab (524288)
{
    const int slab = blockIdx.x / BLOCKS_PER_SLAB;
    const int blk  = blockIdx.x % BLOCKS_PER_SLAB;
    const int c    = slab % NCHAN;              // block-uniform

    const v4f* __restrict__ in4 = (const v4f*)input  + (size_t)slab * S4;
    const v4f* __restrict__ tg4 = (const v4f*)target + (size_t)slab * S4;

    float lsum = 0.0f, lcnt = 0.0f;

    const int stride = BLOCKS_PER_SLAB * THREADS;   // 65536 float4
    int i = blk * THREADS + (int)threadIdx.x;

    for (; i + 3 * stride < S4; i += 4 * stride) {   // 2 iterations
        v4f p0 = ntload(in4 + i);
        v4f p1 = ntload(in4 + i +     stride);
        v4f p2 = ntload(in4 + i + 2 * stride);
        v4f p3 = ntload(in4 + i + 3 * stride);
        v4f t0 = ntload(tg4 + i);
        v4f t1 = ntload(tg4 + i +     stride);
        v4f t2 = ntload(tg4 + i + 2 * stride);
        v4f t3 = ntload(tg4 + i + 3 * stride);
        acc4(p0, t0, lsum, lcnt);
        acc4(p1, t1, lsum, lcnt);
        acc4(p2, t2, lsum, lcnt);
        acc4(p3, t3, lsum, lcnt);
    }
    for (; i < S4; i += stride)   // remainder (none for 524288)
        acc4(ntload(in4 + i), ntload(tg4 + i), lsum, lcnt);

    // wave (64-lane) reduction
#pragma unroll
    for (int off = 32; off > 0; off >>= 1) {
        lsum += __shfl_down(lsum, off, 64);
        lcnt += __shfl_down(lcnt, off, 64);
    }

    __shared__ float wsum[THREADS / 64];
    __shared__ float wcnt[THREADS / 64];
    const int lane = threadIdx.x & 63;
    const int wave = threadIdx.x >> 6;
    if (lane == 0) { wsum[wave] = lsum; wcnt[wave] = lcnt; }
    __syncthreads();
    if (threadIdx.x == 0) {
        float s = 0.0f, n = 0.0f;
#pragma unroll
        for (int w = 0; w < THREADS / 64; ++w) { s += wsum[w]; n += wcnt[w]; }
        const int e = c * ENTRIES_PER_CHAN + (slab / NCHAN) * BLOCKS_PER_SLAB + blk;
        psum[e] = s;          // plain stores, distinct addresses: NO atomics
        pcnt[e] = n;
    }
}

__global__ __launch_bounds__(THREADS) void bce_final(
    const float* __restrict__ psum,
    const float* __restrict__ pcnt,
    float* __restrict__ out,
    float per_chan_total)
{
    const int tid = (int)threadIdx.x;
    float s[NCHAN], n[NCHAN];
#pragma unroll
    for (int c = 0; c < NCHAN; ++c) {
        s[c] = 0.0f; n[c] = 0.0f;
#pragma unroll
        for (int e = 0; e < EPT; ++e) {
            const int b = c * ENTRIES_PER_CHAN + e * THREADS + tid;
            s[c] += psum[b];
            n[c] += pcnt[b];
        }
    }
#pragma unroll
    for (int off = 32; off > 0; off >>= 1) {
#pragma unroll
        for (int c = 0; c < NCHAN; ++c) {
            s[c] += __shfl_down(s[c], off, 64);
            n[c] += __shfl_down(n[c], off, 64);
        }
    }
    __shared__ float ws[THREADS / 64][NCHAN], wn[THREADS / 64][NCHAN];
    const int lane = tid & 63, wave = tid >> 6;
    if (lane == 0) {
#pragma unroll
        for (int c = 0; c < NCHAN; ++c) { ws[wave][c] = s[c]; wn[wave][c] = n[c]; }
    }
    __syncthreads();
    if (tid == 0) {
        float acc = 0.0f;
#pragma unroll
        for (int c = 0; c < NCHAN; ++c) {
            float ssum = 0.0f, ncnt = 0.0f;
#pragma unroll
            for (int w = 0; w < THREADS / 64; ++w) { ssum += ws[w][c]; ncnt += wn[w][c]; }
            float w8  = (ncnt > 0.0f) ? (per_chan_total / fmaxf(ncnt, 1.0f)) : 1000.0f;
            float bce = -(ssum / per_chan_total);
            acc += w8 * bce;
        }
        out[0] = acc / (float)NCHAN;
    }
}

extern "C" void kernel_launch(void* const* d_in, const int* in_sizes, int n_in,
                              void* d_out, int out_size, void* d_ws, size_t ws_size,
                              hipStream_t stream)
{
    const float* input  = (const float*)d_in[0];
    const float* target = (const float*)d_in[1];
    float*       out    = (float*)d_out;

    const int nentry = NCHAN * ENTRIES_PER_CHAN;          // 3072
    float* psum = (float*)d_ws;
    float* pcnt = (float*)d_ws + nentry;

    const long long total = (long long)in_sizes[0];        // 25,165,824
    const int       S4    = (int)(total / (NSLABS * 4));    // 524,288
    const float     M     = (float)(total / NCHAN);         // 8,388,608

    bce_partial<<<NSLABS * BLOCKS_PER_SLAB, THREADS, 0, stream>>>(
        input, target, psum, pcnt, S4);
    bce_final<<<1, THREADS, 0, stream>>>(psum, pcnt, out, M);
}